// Round 1
// baseline (14178.458 us; speedup 1.0000x reference)
//
#include <hip/hip_runtime.h>
#include <hip/hip_cooperative_groups.h>

namespace cg = cooperative_groups;

// Problem constants
#define Bb 128
#define Tt 256
#define Hh 512
#define Ee 300

// ws layout (in unsigned shorts / bf16 elements):
//  h0buf [2 parity][2 plane(hi/lo)][128][512]
//  h1buf [2][2][128][512]
//  w0lo packed frags [104 kg][2048 col][8]   (W0 extended to K=832: 0..299 x, 300..319 zero, 320..831 h)
//  w1lo packed frags [128 kg][2048 col][8]
#define H1OFF   (2*2*128*512)
#define W0LOOFF (2*H1OFF)
#define W1LOOFF (W0LOOFF + 104*2048*8)
// total = 4,325,376 shorts = 8,650,752 bytes of ws

typedef __attribute__((ext_vector_type(8))) short bh8;   // 8 x bf16 (as raw shorts)
typedef __attribute__((ext_vector_type(4))) float f4;

__device__ inline unsigned short bf_of(float f) {
    unsigned int u = __float_as_uint(f);
    return (unsigned short)((u + 0x7FFFu + ((u >> 16) & 1u)) >> 16);
}
__device__ inline unsigned short bf_hi(float f, float& fh) {
    unsigned int u = __float_as_uint(f);
    unsigned int hb = (u + 0x7FFFu + ((u >> 16) & 1u)) >> 16;
    fh = __uint_as_float(hb << 16);
    return (unsigned short)hb;
}
__device__ inline float bf2f(unsigned short s) {
    return __uint_as_float(((unsigned int)s) << 16);
}
__device__ inline float sigm(float x) { return 1.f / (1.f + expf(-x)); }

// ---------------- pre-pack W lo-planes into ws (frag-contiguous) ----------------
__global__ __launch_bounds__(256) void prepack(const float* __restrict__ W0,
                                               const float* __restrict__ W1,
                                               unsigned short* __restrict__ ws) {
    unsigned short* w0lo = ws + W0LOOFF;
    unsigned short* w1lo = ws + W1LOOFF;
    int idx = blockIdx.x * 256 + threadIdx.x;
    if (idx < 104 * 2048) {
        int kg = idx >> 11, col = idx & 2047;
        unsigned short tmp[8];
#pragma unroll
        for (int j = 0; j < 8; j++) {
            int k = kg * 8 + j;
            float w = 0.f;
            if (k < 300) w = W0[k * 2048 + col];
            else if (k >= 320) w = W0[(k - 20) * 2048 + col];
            float fh; bf_hi(w, fh);
            tmp[j] = bf_of(w - fh);
        }
#pragma unroll
        for (int j = 0; j < 8; j++) w0lo[(size_t)idx * 8 + j] = tmp[j];
    } else {
        idx -= 104 * 2048;
        if (idx < 128 * 2048) {
            int kg = idx >> 11, col = idx & 2047;
            unsigned short tmp[8];
#pragma unroll
            for (int j = 0; j < 8; j++) {
                int k = kg * 8 + j;
                float w = W1[k * 2048 + col];
                float fh; bf_hi(w, fh);
                tmp[j] = bf_of(w - fh);
            }
#pragma unroll
            for (int j = 0; j < 8; j++) w1lo[(size_t)idx * 8 + j] = tmp[j];
        }
    }
}

// ---------------- persistent cooperative LSTM kernel ----------------
// grid 256 blocks x 256 threads. block = (bq = blockIdx>>7: batch half, hg = blockIdx&127: 4 h-cols)
// Owns gate columns col(c) = (c>>2)*512 + hg*4 + (c&3), c in [0,16), for BOTH layers.
// One grid.sync per phase; phase p: act/GEMM layer1 for t=p-1, layer0 for t=p.
__global__ __launch_bounds__(256, 1) void lstm_coop(
    const int* __restrict__ x, const float* __restrict__ emb,
    const float* __restrict__ W0, const float* __restrict__ b0,
    const float* __restrict__ W1, const float* __restrict__ b1,
    const float* __restrict__ Wd, const float* __restrict__ bd,
    float* __restrict__ out, unsigned short* __restrict__ ws) {

    const int tid  = threadIdx.x;
    const int lane = tid & 63;
    const int wave = tid >> 6;        // 0..3 : m-tile (16 rows each)
    const int quad = lane >> 4;       // 0..3 : k-chunk of 8 in frags
    const int fm   = lane & 15;       // A: m, B: n, C/D: col
    const int bq = blockIdx.x >> 7;
    const int hg = blockIdx.x & 127;

    __shared__ unsigned short w0hi[104 * 16 * 8];  // 26,624 B
    __shared__ unsigned short w1hi[128 * 16 * 8];  // 32,768 B
    __shared__ float          csm[64 * 17];        //  4,352 B   (total 63,744 B)

    unsigned short* h0b = ws;
    unsigned short* h1b = ws + H1OFF;
    const unsigned short* w0lo = ws + W0LOOFF;
    const unsigned short* w1lo = ws + W1LOOFF;

    // --- fill LDS hi-planes of this block's 16 weight columns (frag layout [kg][n][8]) ---
    for (int i = tid; i < 104 * 16 * 8; i += 256) {
        int kg = i >> 7; int rem = i & 127; int n = rem >> 3; int j = rem & 7;
        int k = kg * 8 + j;
        int col = ((n >> 2) << 9) + (hg << 2) + (n & 3);
        float w = 0.f;
        if (k < 300) w = W0[k * 2048 + col];
        else if (k >= 320) w = W0[(k - 20) * 2048 + col];
        w0hi[i] = bf_of(w);
    }
    for (int i = tid; i < 128 * 16 * 8; i += 256) {
        int kg = i >> 7; int rem = i & 127; int n = rem >> 3; int j = rem & 7;
        int k = kg * 8 + j;
        int col = ((n >> 2) << 9) + (hg << 2) + (n & 3);
        w1hi[i] = bf_of(W1[k * 2048 + col]);
    }
    // --- zero-init h0buf parity 0 and h1buf parity 1 (this block's slice) ---
    for (int i = tid; i < 512; i += 256) {
        int plane = i >> 8; int rem = i & 255; int m = rem >> 2; int hc = rem & 3;
        int r = bq * 64 + m; int k = (hg << 2) + hc;
        h0b[((0 * 2 + plane) * 128 + r) * 512 + k] = 0;
        h1b[((1 * 2 + plane) * 128 + r) * 512 + k] = 0;
    }

    float c0s = 0.f, c1s = 0.f;     // persistent cell-state slice (thread -> (m=tid>>2, hc=tid&3))
    cg::grid_group grid = cg::this_grid();
    grid.sync();

    const int arow   = bq * 64 + wave * 16 + fm;  // A-frag row (batch index)
    const int actm   = tid >> 2;                  // 0..63
    const int acthc  = tid & 3;                   // 0..3
    const int actrow = bq * 64 + actm;
    const int actcol = (hg << 2) + acthc;
    // frag-contiguous lo-plane column base for this lane's n
    const size_t locol = (size_t)(((fm >> 2) << 9) + (hg << 2) + (fm & 3)) * 8;

    for (int p = 0; p <= Tt; ++p) {
        const int par = p & 1, wpar = 1 - (p & 1);

        if (p >= 1) {   // ---- layer 1 for t = p-1 : g1 = [h0(p-1) | h1(p-2)] @ W1 ----
            f4 acc = {0.f, 0.f, 0.f, 0.f};
            const unsigned short* h0hi = h0b + ((par * 2 + 0) * 128 + arow) * 512;
            const unsigned short* h0lo = h0b + ((par * 2 + 1) * 128 + arow) * 512;
            const unsigned short* h1hi = h1b + ((par * 2 + 0) * 128 + arow) * 512;
            const unsigned short* h1lo = h1b + ((par * 2 + 1) * 128 + arow) * 512;
#pragma unroll 4
            for (int kt = 0; kt < 32; kt++) {
                int ko = kt * 32 + quad * 8;
                bh8 ahi, alo;
                if (kt < 16) { ahi = *(const bh8*)(h0hi + ko);        alo = *(const bh8*)(h0lo + ko); }
                else         { ahi = *(const bh8*)(h1hi + (ko - 512)); alo = *(const bh8*)(h1lo + (ko - 512)); }
                int kg = kt * 4 + quad;
                bh8 wh = *(const bh8*)&w1hi[(kg * 16 + fm) * 8];
                bh8 wl = *(const bh8*)(w1lo + (size_t)kg * 2048 * 8 + locol);
                acc = __builtin_amdgcn_mfma_f32_16x16x32_bf16(ahi, wh, acc, 0, 0, 0);
                acc = __builtin_amdgcn_mfma_f32_16x16x32_bf16(ahi, wl, acc, 0, 0, 0);
                acc = __builtin_amdgcn_mfma_f32_16x16x32_bf16(alo, wh, acc, 0, 0, 0);
            }
#pragma unroll
            for (int r = 0; r < 4; r++) csm[(wave * 16 + quad * 4 + r) * 17 + fm] = acc[r];
            __syncthreads();
            {   // activation + state update (i,j,f,o at c = hc, 4+hc, 8+hc, 12+hc)
                float gi = csm[actm * 17 + acthc]      + b1[actcol];
                float gj = csm[actm * 17 + 4 + acthc]  + b1[512 + actcol];
                float gf = csm[actm * 17 + 8 + acthc]  + b1[1024 + actcol];
                float go = csm[actm * 17 + 12 + acthc] + b1[1536 + actcol];
                c1s = c1s * sigm(gf + 1.f) + sigm(gi) * tanhf(gj);
                float h = tanhf(c1s) * sigm(go);
                float fh; unsigned short hb = bf_hi(h, fh);
                h1b[((wpar * 2 + 0) * 128 + actrow) * 512 + actcol] = hb;
                h1b[((wpar * 2 + 1) * 128 + actrow) * 512 + actcol] = bf_of(h - fh);
            }
            __syncthreads();
        }

        if (p < Tt) {   // ---- layer 0 for t = p : g0 = x(p)@W0x + h0(p-1)@W0h ----
            f4 acc = {0.f, 0.f, 0.f, 0.f};
            int xi = x[arow * Tt + p];
            xi = (xi < 0) ? 0 : ((xi >= 50000) ? 49999 : xi);
            const float* embrow = emb + (size_t)xi * 300;
            const unsigned short* h0hi = h0b + ((par * 2 + 0) * 128 + arow) * 512;
            const unsigned short* h0lo = h0b + ((par * 2 + 1) * 128 + arow) * 512;
#pragma unroll 2
            for (int kt = 0; kt < 26; kt++) {
                bh8 ahi, alo;
                if (kt < 10) {          // x part, K 0..319 (300..319 zero-padded)
                    int kbase = kt * 32 + quad * 8;
                    float v[8];
                    if (kt < 9) {
                        f4 u0 = *(const f4*)(embrow + kbase);
                        f4 u1 = *(const f4*)(embrow + kbase + 4);
#pragma unroll
                        for (int e = 0; e < 4; e++) { v[e] = u0[e]; v[4 + e] = u1[e]; }
                    } else {
#pragma unroll
                        for (int e = 0; e < 8; e++) { int kk = kbase + e; v[e] = (kk < 300) ? embrow[kk] : 0.f; }
                    }
#pragma unroll
                    for (int e = 0; e < 8; e++) { float fh; ahi[e] = (short)bf_hi(v[e], fh); alo[e] = (short)bf_of(v[e] - fh); }
                } else {                // h part, K 320..831 -> h0(p-1)
                    int k2 = kt * 32 - 320 + quad * 8;
                    ahi = *(const bh8*)(h0hi + k2);
                    alo = *(const bh8*)(h0lo + k2);
                }
                int kg = kt * 4 + quad;
                bh8 wh = *(const bh8*)&w0hi[(kg * 16 + fm) * 8];
                bh8 wl = *(const bh8*)(w0lo + (size_t)kg * 2048 * 8 + locol);
                acc = __builtin_amdgcn_mfma_f32_16x16x32_bf16(ahi, wh, acc, 0, 0, 0);
                acc = __builtin_amdgcn_mfma_f32_16x16x32_bf16(ahi, wl, acc, 0, 0, 0);
                acc = __builtin_amdgcn_mfma_f32_16x16x32_bf16(alo, wh, acc, 0, 0, 0);
            }
#pragma unroll
            for (int r = 0; r < 4; r++) csm[(wave * 16 + quad * 4 + r) * 17 + fm] = acc[r];
            __syncthreads();
            {
                float gi = csm[actm * 17 + acthc]      + b0[actcol];
                float gj = csm[actm * 17 + 4 + acthc]  + b0[512 + actcol];
                float gf = csm[actm * 17 + 8 + acthc]  + b0[1024 + actcol];
                float go = csm[actm * 17 + 12 + acthc] + b0[1536 + actcol];
                c0s = c0s * sigm(gf + 1.f) + sigm(gi) * tanhf(gj);
                float h = tanhf(c0s) * sigm(go);
                float fh; unsigned short hb = bf_hi(h, fh);
                h0b[((wpar * 2 + 0) * 128 + actrow) * 512 + actcol] = hb;
                h0b[((wpar * 2 + 1) * 128 + actrow) * 512 + actcol] = bf_of(h - fh);
            }
        }
        grid.sync();
    }

    // ---- final logits: h1(T-1) lives in h1buf parity 1 ----
    if (blockIdx.x == 0) {
        int b = tid >> 1, jj = tid & 1;
        float sum = bd[jj];
        const unsigned short* hh = h1b + ((1 * 2 + 0) * 128 + b) * 512;
        const unsigned short* hl = h1b + ((1 * 2 + 1) * 128 + b) * 512;
        for (int k = 0; k < 512; k++) {
            float h = bf2f(hh[k]) + bf2f(hl[k]);
            sum += h * Wd[k * 2 + jj];
        }
        out[b * 2 + jj] = sum;
    }
}

extern "C" void kernel_launch(void* const* d_in, const int* in_sizes, int n_in,
                              void* d_out, int out_size, void* d_ws, size_t ws_size,
                              hipStream_t stream) {
    const int*   x   = (const int*)d_in[0];
    const float* emb = (const float*)d_in[1];
    const float* W0  = (const float*)d_in[2];
    const float* b0  = (const float*)d_in[3];
    const float* W1  = (const float*)d_in[4];
    const float* b1  = (const float*)d_in[5];
    const float* Wd  = (const float*)d_in[6];
    const float* bd  = (const float*)d_in[7];
    float* out = (float*)d_out;
    unsigned short* ws = (unsigned short*)d_ws;

    hipLaunchKernelGGL(prepack, dim3(1856), dim3(256), 0, stream, W0, W1, ws);

    void* args[] = { (void*)&x, (void*)&emb, (void*)&W0, (void*)&b0, (void*)&W1,
                     (void*)&b1, (void*)&Wd, (void*)&bd, (void*)&out, (void*)&ws };
    hipLaunchCooperativeKernel((void*)lstm_coop, dim3(256), dim3(256), args, 0, stream);
}

// Round 2
// 10963.025 us; speedup vs baseline: 1.2933x; 1.2933x over previous
//
#include <hip/hip_runtime.h>

// Problem constants
#define Bb 128
#define Tt 256
#define NB 256

// ws layout (element = unsigned short unless noted):
//  flags   : 256 blocks x 32 ints (128B apart)          [32 KB]
//  h0hi[2][128][512], h0lo[2][128][512]                 (parity, row, col)
//  h1hi[2][128][512], h1lo[2][128][512]
//  w0lo packed frags [104 kg][2048 col][8]   (W0 extended to K=832: 0..299 x, 300..319 zero, 320..831 h)
//  w1lo packed frags [128 kg][2048 col][8]
#define FLAGS_SHORTS (256 * 32 * 2)
#define H0HI  (FLAGS_SHORTS)
#define H0LO  (H0HI + 2 * 128 * 512)
#define H1HI  (H0LO + 2 * 128 * 512)
#define H1LO  (H1HI + 2 * 128 * 512)
#define W0LOOFF (H1LO + 2 * 128 * 512)
#define W1LOOFF (W0LOOFF + 104 * 2048 * 8)
// total approx 8.68 MB of ws

typedef __attribute__((ext_vector_type(8))) short bh8;   // 8 x bf16 (as raw shorts)
typedef __attribute__((ext_vector_type(4))) float f4;

__device__ inline unsigned short bf_of(float f) {
    unsigned int u = __float_as_uint(f);
    return (unsigned short)((u + 0x7FFFu + ((u >> 16) & 1u)) >> 16);
}
__device__ inline unsigned short bf_hi(float f, float& fh) {
    unsigned int u = __float_as_uint(f);
    unsigned int hb = (u + 0x7FFFu + ((u >> 16) & 1u)) >> 16;
    fh = __uint_as_float(hb << 16);
    return (unsigned short)hb;
}
__device__ inline float bf2f(unsigned short s) {
    return __uint_as_float(((unsigned int)s) << 16);
}
__device__ inline float sigm(float x) { return 1.f / (1.f + expf(-x)); }

// ---------------- pre-pack W lo-planes into ws (frag-contiguous) ----------------
__global__ __launch_bounds__(256) void prepack(const float* __restrict__ W0,
                                               const float* __restrict__ W1,
                                               unsigned short* __restrict__ ws) {
    unsigned short* w0lo = ws + W0LOOFF;
    unsigned short* w1lo = ws + W1LOOFF;
    int idx = blockIdx.x * 256 + threadIdx.x;
    if (idx < 104 * 2048) {
        int kg = idx >> 11, col = idx & 2047;
        unsigned short tmp[8];
#pragma unroll
        for (int j = 0; j < 8; j++) {
            int k = kg * 8 + j;
            float w = 0.f;
            if (k < 300) w = W0[k * 2048 + col];
            else if (k >= 320) w = W0[(k - 20) * 2048 + col];
            float fh; bf_hi(w, fh);
            tmp[j] = bf_of(w - fh);
        }
#pragma unroll
        for (int j = 0; j < 8; j++) w0lo[(size_t)idx * 8 + j] = tmp[j];
    } else {
        idx -= 104 * 2048;
        if (idx < 128 * 2048) {
            int kg = idx >> 11, col = idx & 2047;
            unsigned short tmp[8];
#pragma unroll
            for (int j = 0; j < 8; j++) {
                int k = kg * 8 + j;
                float w = W1[k * 2048 + col];
                float fh; bf_hi(w, fh);
                tmp[j] = bf_of(w - fh);
            }
#pragma unroll
            for (int j = 0; j < 8; j++) w1lo[(size_t)idx * 8 + j] = tmp[j];
        }
    }
}

// Distributed flag barrier: one release-store per block (its own cacheline),
// each of 256 threads polls one block's flag (parallel IF$ reads, no RMW
// serialization like cg::grid_group::sync). __threadfence() after the poll
// (waitcnt + wb + L2 inv, agent scope) makes normal loads of cross-XCD h
// data safe; h stores go straight to IF$ via agent-scope atomic stores.
__device__ inline void gbarrier(int* __restrict__ flags, int tid, int bid, int target) {
    __syncthreads();   // all threads' h-stores issued AND vmcnt-drained (syncthreads semantics)
    if (tid == 0)
        __hip_atomic_store(flags + bid * 32, target, __ATOMIC_RELEASE, __HIP_MEMORY_SCOPE_AGENT);
    while (__hip_atomic_load(flags + tid * 32, __ATOMIC_RELAXED, __HIP_MEMORY_SCOPE_AGENT) < target)
        __builtin_amdgcn_s_sleep(1);
    __syncthreads();
    __threadfence();   // acquire: invalidate stale L1/L2 so normal loads see fresh h
}

// ---------------- persistent cooperative LSTM kernel ----------------
// grid 256 blocks x 256 threads. block = (bq = blockIdx>>7: batch half, hg = blockIdx&127: 4 h-cols)
// Owns gate columns col(c) = (c>>2)*512 + hg*4 + (c&3), c in [0,16), for BOTH layers.
// One flag-barrier per phase; phase p: layer1 for t=p-1, layer0 for t=p.
__global__ __launch_bounds__(256, 1) void lstm_coop(
    const int* __restrict__ x, const float* __restrict__ emb,
    const float* __restrict__ W0, const float* __restrict__ b0,
    const float* __restrict__ W1, const float* __restrict__ b1,
    const float* __restrict__ Wd, const float* __restrict__ bd,
    float* __restrict__ out, unsigned short* __restrict__ ws) {

    const int tid  = threadIdx.x;
    const int lane = tid & 63;
    const int wave = tid >> 6;        // 0..3 : m-tile (16 rows each)
    const int quad = lane >> 4;       // 0..3 : k-chunk of 8 in frags
    const int fm   = lane & 15;       // A: m, B: n, C/D: col
    const int bq = blockIdx.x >> 7;
    const int hg = blockIdx.x & 127;

    __shared__ unsigned short w0hi[104 * 16 * 8];  // 26,624 B
    __shared__ unsigned short w1hi[128 * 16 * 8];  // 32,768 B
    __shared__ float          csm[64 * 17];        //  4,352 B   (total 63,744 B)

    int* flags = (int*)ws;
    const unsigned short* w0lo = ws + W0LOOFF;
    const unsigned short* w1lo = ws + W1LOOFF;

    // --- fill LDS hi-planes of this block's 16 weight columns (frag layout [kg][n][8]) ---
    for (int i = tid; i < 104 * 16 * 8; i += 256) {
        int kg = i >> 7; int rem = i & 127; int n = rem >> 3; int j = rem & 7;
        int k = kg * 8 + j;
        int col = ((n >> 2) << 9) + (hg << 2) + (n & 3);
        float w = 0.f;
        if (k < 300) w = W0[k * 2048 + col];
        else if (k >= 320) w = W0[(k - 20) * 2048 + col];
        w0hi[i] = bf_of(w);
    }
    for (int i = tid; i < 128 * 16 * 8; i += 256) {
        int kg = i >> 7; int rem = i & 127; int n = rem >> 3; int j = rem & 7;
        int k = kg * 8 + j;
        int col = ((n >> 2) << 9) + (hg << 2) + (n & 3);
        w1hi[i] = bf_of(W1[k * 2048 + col]);
    }
    // --- zero-init this block's h cells: h0 parity 0 and h1 parity 1 (coherent stores) ---
    if (tid < 128) {
        int row = bq * 64 + (tid >> 1);
        int col = (hg << 2) + ((tid & 1) << 1);   // even col, covers col..col+1 as one uint
        unsigned int* p0h = (unsigned int*)(ws + H0HI + (0 * 128 + row) * 512 + col);
        unsigned int* p0l = (unsigned int*)(ws + H0LO + (0 * 128 + row) * 512 + col);
        unsigned int* p1h = (unsigned int*)(ws + H1HI + (1 * 128 + row) * 512 + col);
        unsigned int* p1l = (unsigned int*)(ws + H1LO + (1 * 128 + row) * 512 + col);
        __hip_atomic_store(p0h, 0u, __ATOMIC_RELAXED, __HIP_MEMORY_SCOPE_AGENT);
        __hip_atomic_store(p0l, 0u, __ATOMIC_RELAXED, __HIP_MEMORY_SCOPE_AGENT);
        __hip_atomic_store(p1h, 0u, __ATOMIC_RELAXED, __HIP_MEMORY_SCOPE_AGENT);
        __hip_atomic_store(p1l, 0u, __ATOMIC_RELAXED, __HIP_MEMORY_SCOPE_AGENT);
    }

    float c0s = 0.f, c1s = 0.f;     // persistent cell-state slice (thread -> (m=tid>>2, hc=tid&3))
    gbarrier(flags, tid, blockIdx.x, 1);

    const int arow   = bq * 64 + wave * 16 + fm;  // A-frag row (batch index)
    const int actm   = tid >> 2;                  // 0..63
    const int acthc  = tid & 3;                   // 0..3
    const int actrow = bq * 64 + actm;
    const int actcol = (hg << 2) + acthc;
    // frag-contiguous lo-plane column base for this lane's n
    const size_t locol = (size_t)(((fm >> 2) << 9) + (hg << 2) + (fm & 3)) * 8;

    for (int p = 0; p <= Tt; ++p) {
        const int par = p & 1, wpar = 1 - (p & 1);
        const unsigned short* h0hi_r = ws + H0HI + (par * 128 + arow) * 512;
        const unsigned short* h0lo_r = ws + H0LO + (par * 128 + arow) * 512;

        if (p >= 1) {   // ---- layer 1 for t = p-1 : g1 = [h0(p-1) | h1(p-2)] @ W1 ----
            f4 acc = {0.f, 0.f, 0.f, 0.f};
            const unsigned short* h1hi_r = ws + H1HI + (par * 128 + arow) * 512;
            const unsigned short* h1lo_r = ws + H1LO + (par * 128 + arow) * 512;
#pragma unroll 4
            for (int kt = 0; kt < 32; kt++) {
                int ko = kt * 32 + quad * 8;
                bh8 ahi, alo;
                if (kt < 16) { ahi = *(const bh8*)(h0hi_r + ko);         alo = *(const bh8*)(h0lo_r + ko); }
                else         { ahi = *(const bh8*)(h1hi_r + (ko - 512)); alo = *(const bh8*)(h1lo_r + (ko - 512)); }
                int kg = kt * 4 + quad;
                bh8 wh = *(const bh8*)&w1hi[(kg * 16 + fm) * 8];
                bh8 wl = *(const bh8*)(w1lo + (size_t)kg * 2048 * 8 + locol);
                acc = __builtin_amdgcn_mfma_f32_16x16x32_bf16(ahi, wh, acc, 0, 0, 0);
                acc = __builtin_amdgcn_mfma_f32_16x16x32_bf16(ahi, wl, acc, 0, 0, 0);
                acc = __builtin_amdgcn_mfma_f32_16x16x32_bf16(alo, wh, acc, 0, 0, 0);
            }
#pragma unroll
            for (int r = 0; r < 4; r++) csm[(wave * 16 + quad * 4 + r) * 17 + fm] = acc[r];
            __syncthreads();
            {   // activation + state update (i,j,f,o at c = hc, 4+hc, 8+hc, 12+hc)
                float gi = csm[actm * 17 + acthc]      + b1[actcol];
                float gj = csm[actm * 17 + 4 + acthc]  + b1[512 + actcol];
                float gf = csm[actm * 17 + 8 + acthc]  + b1[1024 + actcol];
                float go = csm[actm * 17 + 12 + acthc] + b1[1536 + actcol];
                c1s = c1s * sigm(gf + 1.f) + sigm(gi) * tanhf(gj);
                float h = tanhf(c1s) * sigm(go);
                float fh; unsigned short hb = bf_hi(h, fh);
                unsigned short lb = bf_of(h - fh);
                unsigned int ph = (unsigned int)hb | (((unsigned int)(unsigned short)__shfl_xor((int)hb, 1, 64)) << 16);
                unsigned int pl = (unsigned int)lb | (((unsigned int)(unsigned short)__shfl_xor((int)lb, 1, 64)) << 16);
                if (!(acthc & 1)) {
                    unsigned int* dh = (unsigned int*)(ws + H1HI + (wpar * 128 + actrow) * 512 + actcol);
                    unsigned int* dl = (unsigned int*)(ws + H1LO + (wpar * 128 + actrow) * 512 + actcol);
                    __hip_atomic_store(dh, ph, __ATOMIC_RELAXED, __HIP_MEMORY_SCOPE_AGENT);
                    __hip_atomic_store(dl, pl, __ATOMIC_RELAXED, __HIP_MEMORY_SCOPE_AGENT);
                }
            }
            __syncthreads();
        }

        if (p < Tt) {   // ---- layer 0 for t = p : g0 = x(p)@W0x + h0(p-1)@W0h ----
            f4 acc = {0.f, 0.f, 0.f, 0.f};
            int xi = x[arow * Tt + p];
            xi = (xi < 0) ? 0 : ((xi >= 50000) ? 49999 : xi);
            const float* embrow = emb + (size_t)xi * 300;
#pragma unroll 2
            for (int kt = 0; kt < 26; kt++) {
                bh8 ahi, alo;
                if (kt < 10) {          // x part, K 0..319 (300..319 zero-padded)
                    int kbase = kt * 32 + quad * 8;
                    float v[8];
                    if (kt < 9) {
                        f4 u0 = *(const f4*)(embrow + kbase);
                        f4 u1 = *(const f4*)(embrow + kbase + 4);
#pragma unroll
                        for (int e = 0; e < 4; e++) { v[e] = u0[e]; v[4 + e] = u1[e]; }
                    } else {
#pragma unroll
                        for (int e = 0; e < 8; e++) { int kk = kbase + e; v[e] = (kk < 300) ? embrow[kk] : 0.f; }
                    }
#pragma unroll
                    for (int e = 0; e < 8; e++) { float fh; ahi[e] = (short)bf_hi(v[e], fh); alo[e] = (short)bf_of(v[e] - fh); }
                } else {                // h part, K 320..831 -> h0(p-1)
                    int k2 = kt * 32 - 320 + quad * 8;
                    ahi = *(const bh8*)(h0hi_r + k2);
                    alo = *(const bh8*)(h0lo_r + k2);
                }
                int kg = kt * 4 + quad;
                bh8 wh = *(const bh8*)&w0hi[(kg * 16 + fm) * 8];
                bh8 wl = *(const bh8*)(w0lo + (size_t)kg * 2048 * 8 + locol);
                acc = __builtin_amdgcn_mfma_f32_16x16x32_bf16(ahi, wh, acc, 0, 0, 0);
                acc = __builtin_amdgcn_mfma_f32_16x16x32_bf16(ahi, wl, acc, 0, 0, 0);
                acc = __builtin_amdgcn_mfma_f32_16x16x32_bf16(alo, wh, acc, 0, 0, 0);
            }
#pragma unroll
            for (int r = 0; r < 4; r++) csm[(wave * 16 + quad * 4 + r) * 17 + fm] = acc[r];
            __syncthreads();
            {
                float gi = csm[actm * 17 + acthc]      + b0[actcol];
                float gj = csm[actm * 17 + 4 + acthc]  + b0[512 + actcol];
                float gf = csm[actm * 17 + 8 + acthc]  + b0[1024 + actcol];
                float go = csm[actm * 17 + 12 + acthc] + b0[1536 + actcol];
                c0s = c0s * sigm(gf + 1.f) + sigm(gi) * tanhf(gj);
                float h = tanhf(c0s) * sigm(go);
                float fh; unsigned short hb = bf_hi(h, fh);
                unsigned short lb = bf_of(h - fh);
                unsigned int ph = (unsigned int)hb | (((unsigned int)(unsigned short)__shfl_xor((int)hb, 1, 64)) << 16);
                unsigned int pl = (unsigned int)lb | (((unsigned int)(unsigned short)__shfl_xor((int)lb, 1, 64)) << 16);
                if (!(acthc & 1)) {
                    unsigned int* dh = (unsigned int*)(ws + H0HI + (wpar * 128 + actrow) * 512 + actcol);
                    unsigned int* dl = (unsigned int*)(ws + H0LO + (wpar * 128 + actrow) * 512 + actcol);
                    __hip_atomic_store(dh, ph, __ATOMIC_RELAXED, __HIP_MEMORY_SCOPE_AGENT);
                    __hip_atomic_store(dl, pl, __ATOMIC_RELAXED, __HIP_MEMORY_SCOPE_AGENT);
                }
            }
        }
        gbarrier(flags, tid, blockIdx.x, p + 2);
    }

    // ---- final logits: h1(T-1) lives in parity 1 ----
    if (blockIdx.x == 0) {
        int b = tid >> 1, jj = tid & 1;
        float sum = bd[jj];
        const unsigned short* hh = ws + H1HI + (1 * 128 + b) * 512;
        const unsigned short* hl = ws + H1LO + (1 * 128 + b) * 512;
        for (int k = 0; k < 512; k++) {
            float h = bf2f(hh[k]) + bf2f(hl[k]);
            sum += h * Wd[k * 2 + jj];
        }
        out[b * 2 + jj] = sum;
    }
}

extern "C" void kernel_launch(void* const* d_in, const int* in_sizes, int n_in,
                              void* d_out, int out_size, void* d_ws, size_t ws_size,
                              hipStream_t stream) {
    const int*   x   = (const int*)d_in[0];
    const float* emb = (const float*)d_in[1];
    const float* W0  = (const float*)d_in[2];
    const float* b0  = (const float*)d_in[3];
    const float* W1  = (const float*)d_in[4];
    const float* b1  = (const float*)d_in[5];
    const float* Wd  = (const float*)d_in[6];
    const float* bd  = (const float*)d_in[7];
    float* out = (float*)d_out;
    unsigned short* ws = (unsigned short*)d_ws;

    hipLaunchKernelGGL(prepack, dim3(1856), dim3(256), 0, stream, W0, W1, ws);

    void* args[] = { (void*)&x, (void*)&emb, (void*)&W0, (void*)&b0, (void*)&W1,
                     (void*)&b1, (void*)&Wd, (void*)&bd, (void*)&out, (void*)&ws };
    hipLaunchCooperativeKernel((void*)lstm_coop, dim3(256), dim3(256), args, 0, stream);
}

// Round 3
// 7438.190 us; speedup vs baseline: 1.9062x; 1.4739x over previous
//
#include <hip/hip_runtime.h>

// Problem constants
#define Bb 128
#define Tt 256
#define NB 256

// ws layout (element = unsigned short unless noted):
//  flags   : 256 blocks x 32 ints (128B apart)          [32 KB]
//  h0hi[2][128][512], h0lo[2][128][512]                 (parity, row, col)
//  h1hi[2][128][512], h1lo[2][128][512]
//  w0lo packed frags [104 kg][2048 col][8]   (W0 extended to K=832: 0..299 x, 300..319 zero, 320..831 h)
//  w1lo packed frags [128 kg][2048 col][8]
#define FLAGS_SHORTS (256 * 32 * 2)
#define H0HI  (FLAGS_SHORTS)
#define H0LO  (H0HI + 2 * 128 * 512)
#define H1HI  (H0LO + 2 * 128 * 512)
#define H1LO  (H1HI + 2 * 128 * 512)
#define W0LOOFF (H1LO + 2 * 128 * 512)
#define W1LOOFF (W0LOOFF + 104 * 2048 * 8)

typedef __attribute__((ext_vector_type(8))) short bh8;   // 8 x bf16 (as raw shorts)
typedef __attribute__((ext_vector_type(4))) float f4;
typedef unsigned long long ull;

__device__ inline unsigned short bf_of(float f) {
    unsigned int u = __float_as_uint(f);
    return (unsigned short)((u + 0x7FFFu + ((u >> 16) & 1u)) >> 16);
}
__device__ inline unsigned short bf_hi(float f, float& fh) {
    unsigned int u = __float_as_uint(f);
    unsigned int hb = (u + 0x7FFFu + ((u >> 16) & 1u)) >> 16;
    fh = __uint_as_float(hb << 16);
    return (unsigned short)hb;
}
__device__ inline float bf2f(unsigned short s) {
    return __uint_as_float(((unsigned int)s) << 16);
}
__device__ inline float sigm(float x) { return 1.f / (1.f + expf(-x)); }

// Coherent 16B A-fragment load: two relaxed agent-scope 8B atomic loads.
// Agent scope => L2-bypass (per-XCD L2 is not agent-coherent), served by IF$.
// No fences needed anywhere: the whole cross-block data path is atomics.
__device__ inline bh8 ldA(const unsigned short* p) {
    union { ull u[2]; bh8 v; } t;
    t.u[0] = __hip_atomic_load((const ull*)p,       __ATOMIC_RELAXED, __HIP_MEMORY_SCOPE_AGENT);
    t.u[1] = __hip_atomic_load((const ull*)(p + 4), __ATOMIC_RELAXED, __HIP_MEMORY_SCOPE_AGENT);
    return t.v;
}

// ---------------- pre-pack W lo-planes into ws (frag-contiguous) ----------------
__global__ __launch_bounds__(256) void prepack(const float* __restrict__ W0,
                                               const float* __restrict__ W1,
                                               unsigned short* __restrict__ ws) {
    unsigned short* w0lo = ws + W0LOOFF;
    unsigned short* w1lo = ws + W1LOOFF;
    int idx = blockIdx.x * 256 + threadIdx.x;
    if (idx < 104 * 2048) {
        int kg = idx >> 11, col = idx & 2047;
        unsigned short tmp[8];
#pragma unroll
        for (int j = 0; j < 8; j++) {
            int k = kg * 8 + j;
            float w = 0.f;
            if (k < 300) w = W0[k * 2048 + col];
            else if (k >= 320) w = W0[(k - 20) * 2048 + col];
            float fh; bf_hi(w, fh);
            tmp[j] = bf_of(w - fh);
        }
#pragma unroll
        for (int j = 0; j < 8; j++) w0lo[(size_t)idx * 8 + j] = tmp[j];
    } else {
        idx -= 104 * 2048;
        if (idx < 128 * 2048) {
            int kg = idx >> 11, col = idx & 2047;
            unsigned short tmp[8];
#pragma unroll
            for (int j = 0; j < 8; j++) {
                int k = kg * 8 + j;
                float w = W1[k * 2048 + col];
                float fh; bf_hi(w, fh);
                tmp[j] = bf_of(w - fh);
            }
#pragma unroll
            for (int j = 0; j < 8; j++) w1lo[(size_t)idx * 8 + j] = tmp[j];
        }
    }
}

// Split barrier, fence-free. Arrive: drain own stores (they are write-through
// agent atomics, so vmcnt(0) == globally visible), block-sync, publish flag.
// Wait: poll (control dependency orders the later atomic h-loads; those bypass
// L2 so no invalidate is needed), then block-sync.
__device__ inline void barrier_arrive(int* __restrict__ flags, int tid, int bid, int target) {
    __builtin_amdgcn_s_waitcnt(0);
    __syncthreads();
    if (tid == 0)
        __hip_atomic_store(flags + bid * 32, target, __ATOMIC_RELAXED, __HIP_MEMORY_SCOPE_AGENT);
}
__device__ inline void barrier_wait(int* __restrict__ flags, int tid, int target) {
    while (__hip_atomic_load(flags + tid * 32, __ATOMIC_RELAXED, __HIP_MEMORY_SCOPE_AGENT) < target)
        __builtin_amdgcn_s_sleep(1);
    __syncthreads();
}

// ---------------- persistent cooperative LSTM kernel ----------------
// grid 256 blocks x 256 threads. block = (bq = blockIdx>>7: batch half, hg = blockIdx&127: 4 h-cols)
__global__ __launch_bounds__(256, 1) void lstm_coop(
    const int* __restrict__ x, const float* __restrict__ emb,
    const float* __restrict__ W0, const float* __restrict__ b0,
    const float* __restrict__ W1, const float* __restrict__ b1,
    const float* __restrict__ Wd, const float* __restrict__ bd,
    float* __restrict__ out, unsigned short* __restrict__ ws) {

    const int tid  = threadIdx.x;
    const int lane = tid & 63;
    const int wave = tid >> 6;        // 0..3 : m-tile (16 rows each)
    const int quad = lane >> 4;       // 0..3 : k-chunk of 8 in frags
    const int fm   = lane & 15;       // A: m, B: n, C/D: col
    const int bq = blockIdx.x >> 7;
    const int hg = blockIdx.x & 127;

    __shared__ unsigned short w0hi[104 * 16 * 8];  // 26,624 B
    __shared__ unsigned short w1hi[128 * 16 * 8];  // 32,768 B
    __shared__ float          csm[64 * 17];        //  4,352 B

    int* flags = (int*)ws;
    const unsigned short* w0lo = ws + W0LOOFF;
    const unsigned short* w1lo = ws + W1LOOFF;

    // --- fill LDS hi-planes of this block's 16 weight columns (frag layout [kg][n][8]) ---
    for (int i = tid; i < 104 * 16 * 8; i += 256) {
        int kg = i >> 7; int rem = i & 127; int n = rem >> 3; int j = rem & 7;
        int k = kg * 8 + j;
        int col = ((n >> 2) << 9) + (hg << 2) + (n & 3);
        float w = 0.f;
        if (k < 300) w = W0[k * 2048 + col];
        else if (k >= 320) w = W0[(k - 20) * 2048 + col];
        w0hi[i] = bf_of(w);
    }
    for (int i = tid; i < 128 * 16 * 8; i += 256) {
        int kg = i >> 7; int rem = i & 127; int n = rem >> 3; int j = rem & 7;
        int k = kg * 8 + j;
        int col = ((n >> 2) << 9) + (hg << 2) + (n & 3);
        w1hi[i] = bf_of(W1[k * 2048 + col]);
    }
    // --- zero-init this block's h cells: h0 parity 0 and h1 parity 1 ---
    if (tid < 128) {
        int row = bq * 64 + (tid >> 1);
        int col = (hg << 2) + ((tid & 1) << 1);
        unsigned int* p0h = (unsigned int*)(ws + H0HI + (0 * 128 + row) * 512 + col);
        unsigned int* p0l = (unsigned int*)(ws + H0LO + (0 * 128 + row) * 512 + col);
        unsigned int* p1h = (unsigned int*)(ws + H1HI + (1 * 128 + row) * 512 + col);
        unsigned int* p1l = (unsigned int*)(ws + H1LO + (1 * 128 + row) * 512 + col);
        __hip_atomic_store(p0h, 0u, __ATOMIC_RELAXED, __HIP_MEMORY_SCOPE_AGENT);
        __hip_atomic_store(p0l, 0u, __ATOMIC_RELAXED, __HIP_MEMORY_SCOPE_AGENT);
        __hip_atomic_store(p1h, 0u, __ATOMIC_RELAXED, __HIP_MEMORY_SCOPE_AGENT);
        __hip_atomic_store(p1l, 0u, __ATOMIC_RELAXED, __HIP_MEMORY_SCOPE_AGENT);
    }

    const int arow   = bq * 64 + wave * 16 + fm;  // A-frag row (batch index)
    const int actm   = tid >> 2;
    const int acthc  = tid & 3;
    const int actrow = bq * 64 + actm;
    const int actcol = (hg << 2) + acthc;
    const size_t locol = (size_t)(((fm >> 2) << 9) + (hg << 2) + (fm & 3)) * 8;

    // biases in registers
    const float b0i = b0[actcol], b0j = b0[512 + actcol], b0f = b0[1024 + actcol], b0o = b0[1536 + actcol];
    const float b1i = b1[actcol], b1j = b1[512 + actcol], b1f = b1[1024 + actcol], b1o = b1[1536 + actcol];

    float c0s = 0.f, c1s = 0.f;

    // x-part GEMM of layer 0 for timestep pp (kt 0..9), recurrence-independent.
    auto xgemm = [&](int pp) -> f4 {
        f4 a = {0.f, 0.f, 0.f, 0.f};
        int xi = x[arow * Tt + pp];
        xi = (xi < 0) ? 0 : ((xi >= 50000) ? 49999 : xi);
        const float* embrow = emb + (size_t)xi * 300;
#pragma unroll
        for (int kt = 0; kt < 10; kt++) {
            int kbase = kt * 32 + quad * 8;
            float v[8];
            if (kt < 9) {
                f4 u0 = *(const f4*)(embrow + kbase);
                f4 u1 = *(const f4*)(embrow + kbase + 4);
#pragma unroll
                for (int e = 0; e < 4; e++) { v[e] = u0[e]; v[4 + e] = u1[e]; }
            } else {
#pragma unroll
                for (int e = 0; e < 8; e++) { int kk = kbase + e; v[e] = (kk < 300) ? embrow[kk] : 0.f; }
            }
            bh8 ahi, alo;
#pragma unroll
            for (int e = 0; e < 8; e++) { float fh; ahi[e] = (short)bf_hi(v[e], fh); alo[e] = (short)bf_of(v[e] - fh); }
            int kg = kt * 4 + quad;
            bh8 wh = *(const bh8*)&w0hi[(kg * 16 + fm) * 8];
            bh8 wl = *(const bh8*)(w0lo + (size_t)kg * 2048 * 8 + locol);
            a = __builtin_amdgcn_mfma_f32_16x16x32_bf16(ahi, wh, a, 0, 0, 0);
            a = __builtin_amdgcn_mfma_f32_16x16x32_bf16(ahi, wl, a, 0, 0, 0);
            a = __builtin_amdgcn_mfma_f32_16x16x32_bf16(alo, wh, a, 0, 0, 0);
        }
        return a;
    };

    barrier_arrive(flags, tid, blockIdx.x, 1);
    f4 accx = xgemm(0);
    barrier_wait(flags, tid, 1);

    for (int p = 0; p <= Tt; ++p) {
        const int par = p & 1, wpar = 1 - (p & 1);
        const unsigned short* h0hi_r = ws + H0HI + (par * 128 + arow) * 512;
        const unsigned short* h0lo_r = ws + H0LO + (par * 128 + arow) * 512;

        if (p >= 1) {   // ---- layer 1 for t = p-1 : g1 = [h0(p-1) | h1(p-2)] @ W1 ----
            f4 acc = {0.f, 0.f, 0.f, 0.f};
            const unsigned short* h1hi_r = ws + H1HI + (par * 128 + arow) * 512;
            const unsigned short* h1lo_r = ws + H1LO + (par * 128 + arow) * 512;
#pragma unroll 8
            for (int kt = 0; kt < 32; kt++) {
                int ko = kt * 32 + quad * 8;
                bh8 ahi, alo;
                if (kt < 16) { ahi = ldA(h0hi_r + ko);       alo = ldA(h0lo_r + ko); }
                else         { ahi = ldA(h1hi_r + ko - 512); alo = ldA(h1lo_r + ko - 512); }
                int kg = kt * 4 + quad;
                bh8 wh = *(const bh8*)&w1hi[(kg * 16 + fm) * 8];
                bh8 wl = *(const bh8*)(w1lo + (size_t)kg * 2048 * 8 + locol);
                acc = __builtin_amdgcn_mfma_f32_16x16x32_bf16(ahi, wh, acc, 0, 0, 0);
                acc = __builtin_amdgcn_mfma_f32_16x16x32_bf16(ahi, wl, acc, 0, 0, 0);
                acc = __builtin_amdgcn_mfma_f32_16x16x32_bf16(alo, wh, acc, 0, 0, 0);
            }
#pragma unroll
            for (int r = 0; r < 4; r++) csm[(wave * 16 + quad * 4 + r) * 17 + fm] = acc[r];
            __syncthreads();
            {
                float gi = csm[actm * 17 + acthc]      + b1i;
                float gj = csm[actm * 17 + 4 + acthc]  + b1j;
                float gf = csm[actm * 17 + 8 + acthc]  + b1f;
                float go = csm[actm * 17 + 12 + acthc] + b1o;
                c1s = c1s * sigm(gf + 1.f) + sigm(gi) * tanhf(gj);
                float h = tanhf(c1s) * sigm(go);
                float fh; unsigned short hb = bf_hi(h, fh);
                unsigned short lb = bf_of(h - fh);
                unsigned int ph = (unsigned int)hb | (((unsigned int)(unsigned short)__shfl_xor((int)hb, 1, 64)) << 16);
                unsigned int pl = (unsigned int)lb | (((unsigned int)(unsigned short)__shfl_xor((int)lb, 1, 64)) << 16);
                if (!(acthc & 1)) {
                    unsigned int* dh = (unsigned int*)(ws + H1HI + (wpar * 128 + actrow) * 512 + actcol);
                    unsigned int* dl = (unsigned int*)(ws + H1LO + (wpar * 128 + actrow) * 512 + actcol);
                    __hip_atomic_store(dh, ph, __ATOMIC_RELAXED, __HIP_MEMORY_SCOPE_AGENT);
                    __hip_atomic_store(dl, pl, __ATOMIC_RELAXED, __HIP_MEMORY_SCOPE_AGENT);
                }
            }
            __syncthreads();
        }

        if (p < Tt) {   // ---- layer 0 h-part for t = p (x-part already in accx) ----
            f4 acc = accx;
#pragma unroll 8
            for (int kt = 10; kt < 26; kt++) {
                int k2 = kt * 32 - 320 + quad * 8;
                bh8 ahi = ldA(h0hi_r + k2);
                bh8 alo = ldA(h0lo_r + k2);
                int kg = kt * 4 + quad;
                bh8 wh = *(const bh8*)&w0hi[(kg * 16 + fm) * 8];
                bh8 wl = *(const bh8*)(w0lo + (size_t)kg * 2048 * 8 + locol);
                acc = __builtin_amdgcn_mfma_f32_16x16x32_bf16(ahi, wh, acc, 0, 0, 0);
                acc = __builtin_amdgcn_mfma_f32_16x16x32_bf16(ahi, wl, acc, 0, 0, 0);
                acc = __builtin_amdgcn_mfma_f32_16x16x32_bf16(alo, wh, acc, 0, 0, 0);
            }
#pragma unroll
            for (int r = 0; r < 4; r++) csm[(wave * 16 + quad * 4 + r) * 17 + fm] = acc[r];
            __syncthreads();
            {
                float gi = csm[actm * 17 + acthc]      + b0i;
                float gj = csm[actm * 17 + 4 + acthc]  + b0j;
                float gf = csm[actm * 17 + 8 + acthc]  + b0f;
                float go = csm[actm * 17 + 12 + acthc] + b0o;
                c0s = c0s * sigm(gf + 1.f) + sigm(gi) * tanhf(gj);
                float h = tanhf(c0s) * sigm(go);
                float fh; unsigned short hb = bf_hi(h, fh);
                unsigned short lb = bf_of(h - fh);
                unsigned int ph = (unsigned int)hb | (((unsigned int)(unsigned short)__shfl_xor((int)hb, 1, 64)) << 16);
                unsigned int pl = (unsigned int)lb | (((unsigned int)(unsigned short)__shfl_xor((int)lb, 1, 64)) << 16);
                if (!(acthc & 1)) {
                    unsigned int* dh = (unsigned int*)(ws + H0HI + (wpar * 128 + actrow) * 512 + actcol);
                    unsigned int* dl = (unsigned int*)(ws + H0LO + (wpar * 128 + actrow) * 512 + actcol);
                    __hip_atomic_store(dh, ph, __ATOMIC_RELAXED, __HIP_MEMORY_SCOPE_AGENT);
                    __hip_atomic_store(dl, pl, __ATOMIC_RELAXED, __HIP_MEMORY_SCOPE_AGENT);
                }
            }
        }

        barrier_arrive(flags, tid, blockIdx.x, p + 2);
        if (p + 1 < Tt) accx = xgemm(p + 1);
        barrier_wait(flags, tid, p + 2);
    }

    // ---- final logits: h1(T-1) lives in parity 1 (read coherently) ----
    if (blockIdx.x == 0) {
        int b = tid >> 1, jj = tid & 1;
        float sum = bd[jj];
        const unsigned short* hh = ws + H1HI + (1 * 128 + b) * 512;
        const unsigned short* hl = ws + H1LO + (1 * 128 + b) * 512;
        for (int k4 = 0; k4 < 512; k4 += 4) {
            ull uh = __hip_atomic_load((const ull*)(hh + k4), __ATOMIC_RELAXED, __HIP_MEMORY_SCOPE_AGENT);
            ull ul = __hip_atomic_load((const ull*)(hl + k4), __ATOMIC_RELAXED, __HIP_MEMORY_SCOPE_AGENT);
#pragma unroll
            for (int e = 0; e < 4; e++) {
                float h = bf2f((unsigned short)(uh >> (16 * e))) + bf2f((unsigned short)(ul >> (16 * e)));
                sum += h * Wd[(k4 + e) * 2 + jj];
            }
        }
        out[b * 2 + jj] = sum;
    }
}

extern "C" void kernel_launch(void* const* d_in, const int* in_sizes, int n_in,
                              void* d_out, int out_size, void* d_ws, size_t ws_size,
                              hipStream_t stream) {
    const int*   x   = (const int*)d_in[0];
    const float* emb = (const float*)d_in[1];
    const float* W0  = (const float*)d_in[2];
    const float* b0  = (const float*)d_in[3];
    const float* W1  = (const float*)d_in[4];
    const float* b1  = (const float*)d_in[5];
    const float* Wd  = (const float*)d_in[6];
    const float* bd  = (const float*)d_in[7];
    float* out = (float*)d_out;
    unsigned short* ws = (unsigned short*)d_ws;

    hipLaunchKernelGGL(prepack, dim3(1856), dim3(256), 0, stream, W0, W1, ws);

    void* args[] = { (void*)&x, (void*)&emb, (void*)&W0, (void*)&b0, (void*)&W1,
                     (void*)&b1, (void*)&Wd, (void*)&bd, (void*)&out, (void*)&ws };
    hipLaunchCooperativeKernel((void*)lstm_coop, dim3(256), dim3(256), args, 0, stream);
}

// Round 5
// 6012.757 us; speedup vs baseline: 2.3581x; 1.2371x over previous
//
#include <hip/hip_runtime.h>

// Problem constants
#define Tt 256

// ws layout in unsigned shorts (fp16 bit patterns / ints for flags):
//  flags : 256 blocks x 32 ints (128B apart)            [32 KB]
//  h0[2 parity][128][512] fp16 ; h1 same                [512 KB each]
//  w0lo packed frags [104 kg][2048 col][8]  (W0 extended to K=832: 0..299 x, 300..319 zero, 320..831 h)
//  w1lo packed frags [128 kg][2048 col][8]  (lo planes = (w - fp16(w))*1024, fp16)
// total = 4,079,616 shorts = 8,159,232 B  — UNDER the 8.68 MB proven-safe R3 budget
// (R4 post-mortem: 15.76 MB ws failed; suspected ws_size overflow — keep ws <= 8.68 MB)
#define FLAGS_SHORTS 16384
#define H0OFF  16384
#define H1OFF  (H0OFF + 2*128*512)
#define W0LOFF (H1OFF + 2*128*512)
#define W1LOFF (W0LOFF + 104*2048*8)

typedef _Float16 h8 __attribute__((ext_vector_type(8)));
typedef float    f4 __attribute__((ext_vector_type(4)));
typedef unsigned long long ull;
typedef unsigned short u16;

#define MFMA __builtin_amdgcn_mfma_f32_16x16x32_f16
#define LOSC (1.0f/1024.0f)

__device__ inline u16 h_bits(float f){ union{_Float16 h; u16 s;} u; u.h=(_Float16)f; return u.s; }
__device__ inline float bits_f(u16 s){ union{u16 s2; _Float16 h;} u; u.s2=s; return (float)u.h; }
__device__ inline float sigm(float x){ return 1.f/(1.f+expf(-x)); }

// Coherent 16B A-fragment load: two relaxed agent-scope 8B atomic loads.
// Agent scope => per-XCD-L2 bypass, served by IF$. No fences anywhere:
// the whole cross-block data path is atomics (proven R2->R3).
__device__ inline h8 ldH(const u16* p){
    union{ ull u[2]; h8 v; } t;
    t.u[0]=__hip_atomic_load((const ull*)p,    __ATOMIC_RELAXED, __HIP_MEMORY_SCOPE_AGENT);
    t.u[1]=__hip_atomic_load((const ull*)(p+4),__ATOMIC_RELAXED, __HIP_MEMORY_SCOPE_AGENT);
    return t.v;
}

// ---------------- pre-pack W lo-planes (fp16, x1024) into ws, frag-contiguous ----------------
__global__ __launch_bounds__(256) void prepack(const float* __restrict__ W0,
                                               const float* __restrict__ W1,
                                               u16* __restrict__ ws) {
    int idx = blockIdx.x * 256 + threadIdx.x;
    if (idx < 104 * 2048) {
        int kg = idx >> 11, col = idx & 2047;
        u16 tl[8];
#pragma unroll
        for (int j = 0; j < 8; j++) {
            int k = kg * 8 + j;
            float w = 0.f;
            if (k < 300) w = W0[k * 2048 + col];
            else if (k >= 320) w = W0[(k - 20) * 2048 + col];
            _Float16 wh = (_Float16)w;
            tl[j] = h_bits((w - (float)wh) * 1024.0f);
        }
#pragma unroll
        for (int j = 0; j < 8; j++) ws[W0LOFF + (size_t)idx*8 + j] = tl[j];
    } else {
        int i2 = idx - 104 * 2048;
        if (i2 < 128 * 2048) {
            int kg = i2 >> 11, col = i2 & 2047;
            u16 tl[8];
#pragma unroll
            for (int j = 0; j < 8; j++) {
                float w = W1[(kg * 8 + j) * 2048 + col];
                _Float16 wh = (_Float16)w;
                tl[j] = h_bits((w - (float)wh) * 1024.0f);
            }
#pragma unroll
            for (int j = 0; j < 8; j++) ws[W1LOFF + (size_t)i2*8 + j] = tl[j];
        }
    }
}

// Fence-free split barrier (proven R3): write-through agent atomics + vmcnt drain,
// distributed per-block flags, pollers use agent atomic loads (L2-bypass => no invalidate).
__device__ inline void barrier_arrive(int* __restrict__ flags, int tid, int bid, int target) {
    __builtin_amdgcn_s_waitcnt(0);
    __syncthreads();
    if (tid == 0)
        __hip_atomic_store(flags + bid * 32, target, __ATOMIC_RELAXED, __HIP_MEMORY_SCOPE_AGENT);
}
__device__ inline void barrier_wait(int* __restrict__ flags, int tid, int target) {
    while (__hip_atomic_load(flags + tid * 32, __ATOMIC_RELAXED, __HIP_MEMORY_SCOPE_AGENT) < target)
        __builtin_amdgcn_s_sleep(1);
    __syncthreads();
}

struct X2 { f4 h, l; };

// ---------------- persistent cooperative LSTM kernel ----------------
// grid 256 blocks x 256 threads. block = (bq = blockIdx>>7: batch half (64 rows),
// hg = blockIdx&127: 4 h-cols -> 16 gate-cols). Exactly R3's proven blocking;
// only the dtype/plane scheme changed (fp16 single-plane A, fp16 hi/lo W 2-pass).
__global__ __launch_bounds__(256, 1) void lstm_coop(
    const int* __restrict__ x, const float* __restrict__ emb,
    const float* __restrict__ W0, const float* __restrict__ b0,
    const float* __restrict__ W1, const float* __restrict__ b1,
    const float* __restrict__ Wd, const float* __restrict__ bd,
    float* __restrict__ out, u16* __restrict__ ws) {

    const int tid  = threadIdx.x;
    const int lane = tid & 63;
    const int wave = tid >> 6;        // 0..3 : m-tile (16 rows each)
    const int quad = lane >> 4;       // 0..3 : k-chunk of 8 in frags
    const int fm   = lane & 15;       // A: m, B: n, C/D: col
    const int bq = blockIdx.x >> 7;
    const int hg = blockIdx.x & 127;

    __shared__ u16   w0hi[104 * 16 * 8];  // 26,624 B (fp16 bits)
    __shared__ u16   w1hi[128 * 16 * 8];  // 32,768 B
    __shared__ float csm[64 * 17];        //  4,352 B  (total 63,744 B — R3-proven)

    int* flags = (int*)ws;
    const u16* w0lo = ws + W0LOFF;
    const u16* w1lo = ws + W1LOFF;

    // --- fill LDS hi-planes (fp16) of this block's 16 weight columns, frag layout [kg][n][8] ---
    for (int i = tid; i < 104 * 16 * 8; i += 256) {
        int kg = i >> 7; int rem = i & 127; int n = rem >> 3; int j = rem & 7;
        int k = kg * 8 + j;
        int col = ((n >> 2) << 9) + (hg << 2) + (n & 3);
        float w = 0.f;
        if (k < 300) w = W0[k * 2048 + col];
        else if (k >= 320) w = W0[(k - 20) * 2048 + col];
        w0hi[i] = h_bits(w);
    }
    for (int i = tid; i < 128 * 16 * 8; i += 256) {
        int kg = i >> 7; int rem = i & 127; int n = rem >> 3; int j = rem & 7;
        int k = kg * 8 + j;
        int col = ((n >> 2) << 9) + (hg << 2) + (n & 3);
        w1hi[i] = h_bits(W1[k * 2048 + col]);
    }
    // --- zero-init this block's h cells: h0 parity 0 and h1 parity 1 ---
    if (tid < 128) {
        int row = bq * 64 + (tid >> 1);
        int col = (hg << 2) + ((tid & 1) << 1);   // even col, uint covers col..col+1
        unsigned int* p0 = (unsigned int*)(ws + H0OFF + (0 * 128 + row) * 512 + col);
        unsigned int* p1 = (unsigned int*)(ws + H1OFF + (1 * 128 + row) * 512 + col);
        __hip_atomic_store(p0, 0u, __ATOMIC_RELAXED, __HIP_MEMORY_SCOPE_AGENT);
        __hip_atomic_store(p1, 0u, __ATOMIC_RELAXED, __HIP_MEMORY_SCOPE_AGENT);
    }

    const int arow   = bq * 64 + wave * 16 + fm;  // A-frag row (batch index)
    const int actm   = tid >> 2;
    const int acthc  = tid & 3;
    const int actrow = bq * 64 + actm;
    const int actcol = (hg << 2) + acthc;
    // frag-contiguous lo-plane column base for this lane's n (gate = fm>>2, hc = fm&3)
    const size_t locol = (size_t)(((fm >> 2) << 9) + (hg << 2) + (fm & 3)) * 8;

    const float b0i = b0[actcol], b0j = b0[512+actcol], b0f = b0[1024+actcol], b0o = b0[1536+actcol];
    const float b1i = b1[actcol], b1j = b1[512+actcol], b1f = b1[1024+actcol], b1o = b1[1536+actcol];

    float c0s = 0.f, c1s = 0.f;

    // x-part GEMM of layer 0 for timestep pp (kt 0..9), recurrence-independent;
    // runs inside the barrier arrive->wait window.
    auto xgemm = [&](int pp) -> X2 {
        X2 a; a.h = (f4){0,0,0,0}; a.l = a.h;
        int xi = x[arow * Tt + pp];
        xi = (xi < 0) ? 0 : ((xi >= 50000) ? 49999 : xi);
        const float* embrow = emb + (size_t)xi * 300;
#pragma unroll
        for (int kt = 0; kt < 10; kt++) {
            int kbase = kt * 32 + quad * 8;
            h8 af;
            if (kt < 9) {
                f4 u0 = *(const f4*)(embrow + kbase);
                f4 u1 = *(const f4*)(embrow + kbase + 4);
#pragma unroll
                for (int e = 0; e < 4; e++) { af[e] = (_Float16)u0[e]; af[4+e] = (_Float16)u1[e]; }
            } else {
#pragma unroll
                for (int e = 0; e < 8; e++) { int kk = kbase + e; af[e] = (_Float16)((kk < 300) ? embrow[kk] : 0.f); }
            }
            int kg = kt * 4 + quad;
            a.h = MFMA(af, *(const h8*)&w0hi[(kg * 16 + fm) * 8],            a.h, 0,0,0);
            a.l = MFMA(af, *(const h8*)(w0lo + (size_t)kg * 2048 * 8 + locol), a.l, 0,0,0);
        }
        return a;
    };

    barrier_arrive(flags, tid, blockIdx.x, 1);
    X2 accx = xgemm(0);
    barrier_wait(flags, tid, 1);

    for (int p = 0; p <= Tt; ++p) {
        const int par = p & 1, wpar = 1 - (p & 1);
        const u16* h0r = ws + H0OFF + ((size_t)(par * 128 + arow)) * 512;

        if (p >= 1) {   // ---- layer 1 for t=p-1 : g1 = [h0(p-1) | h1(p-2)] @ W1 ----
            f4 aH = (f4){0,0,0,0}, aL = aH;
            const u16* h1r = ws + H1OFF + ((size_t)(par * 128 + arow)) * 512;
#pragma unroll 8
            for (int kt = 0; kt < 32; kt++) {
                int ko = kt * 32 + quad * 8;
                h8 af = (kt < 16) ? ldH(h0r + ko) : ldH(h1r + ko - 512);
                int kg = kt * 4 + quad;
                aH = MFMA(af, *(const h8*)&w1hi[(kg * 16 + fm) * 8],            aH, 0,0,0);
                aL = MFMA(af, *(const h8*)(w1lo + (size_t)kg * 2048 * 8 + locol), aL, 0,0,0);
            }
#pragma unroll
            for (int r = 0; r < 4; r++)
                csm[(wave * 16 + quad * 4 + r) * 17 + fm] = aH[r] + aL[r] * LOSC;
            __syncthreads();
            {   // activation: gates i,j,f,o at in-block cols hc, 4+hc, 8+hc, 12+hc
                float gi = csm[actm * 17 + acthc]      + b1i;
                float gj = csm[actm * 17 + 4 + acthc]  + b1j;
                float gf = csm[actm * 17 + 8 + acthc]  + b1f;
                float go = csm[actm * 17 + 12 + acthc] + b1o;
                c1s = c1s * sigm(gf + 1.f) + sigm(gi) * tanhf(gj);
                float h = tanhf(c1s) * sigm(go);
                u16 hb = h_bits(h);
                unsigned int pk = (unsigned int)hb | (((unsigned int)(u16)__shfl_xor((int)hb, 1, 64)) << 16);
                if (!(acthc & 1)) {
                    unsigned int* d = (unsigned int*)(ws + H1OFF + ((size_t)(wpar * 128 + actrow)) * 512 + actcol);
                    __hip_atomic_store(d, pk, __ATOMIC_RELAXED, __HIP_MEMORY_SCOPE_AGENT);
                }
            }
            __syncthreads();
        }

        if (p < Tt) {   // ---- layer 0 h-part for t=p (x-part already in accx) ----
            f4 aH = accx.h, aL = accx.l;
#pragma unroll 8
            for (int kt = 10; kt < 26; kt++) {
                int k2 = kt * 32 - 320 + quad * 8;
                h8 af = ldH(h0r + k2);
                int kg = kt * 4 + quad;
                aH = MFMA(af, *(const h8*)&w0hi[(kg * 16 + fm) * 8],            aH, 0,0,0);
                aL = MFMA(af, *(const h8*)(w0lo + (size_t)kg * 2048 * 8 + locol), aL, 0,0,0);
            }
#pragma unroll
            for (int r = 0; r < 4; r++)
                csm[(wave * 16 + quad * 4 + r) * 17 + fm] = aH[r] + aL[r] * LOSC;
            __syncthreads();
            {
                float gi = csm[actm * 17 + acthc]      + b0i;
                float gj = csm[actm * 17 + 4 + acthc]  + b0j;
                float gf = csm[actm * 17 + 8 + acthc]  + b0f;
                float go = csm[actm * 17 + 12 + acthc] + b0o;
                c0s = c0s * sigm(gf + 1.f) + sigm(gi) * tanhf(gj);
                float h = tanhf(c0s) * sigm(go);
                u16 hb = h_bits(h);
                unsigned int pk = (unsigned int)hb | (((unsigned int)(u16)__shfl_xor((int)hb, 1, 64)) << 16);
                if (!(acthc & 1)) {
                    unsigned int* d = (unsigned int*)(ws + H0OFF + ((size_t)(wpar * 128 + actrow)) * 512 + actcol);
                    __hip_atomic_store(d, pk, __ATOMIC_RELAXED, __HIP_MEMORY_SCOPE_AGENT);
                }
            }
        }

        barrier_arrive(flags, tid, blockIdx.x, p + 2);
        if (p + 1 < Tt) accx = xgemm(p + 1);
        barrier_wait(flags, tid, p + 2);
    }

    // ---- final logits: h1(T-1) lives in parity 1 ----
    if (blockIdx.x == 0) {
        int b = tid >> 1, jj = tid & 1;
        float sum = bd[jj];
        const u16* hh = ws + H1OFF + (1 * 128 + b) * 512;
        for (int k4 = 0; k4 < 512; k4 += 4) {
            ull u = __hip_atomic_load((const ull*)(hh + k4), __ATOMIC_RELAXED, __HIP_MEMORY_SCOPE_AGENT);
#pragma unroll
            for (int e = 0; e < 4; e++)
                sum += bits_f((u16)(u >> (16 * e))) * Wd[(k4 + e) * 2 + jj];
        }
        out[b * 2 + jj] = sum;
    }
}

extern "C" void kernel_launch(void* const* d_in, const int* in_sizes, int n_in,
                              void* d_out, int out_size, void* d_ws, size_t ws_size,
                              hipStream_t stream) {
    const int*   x   = (const int*)d_in[0];
    const float* emb = (const float*)d_in[1];
    const float* W0  = (const float*)d_in[2];
    const float* b0  = (const float*)d_in[3];
    const float* W1  = (const float*)d_in[4];
    const float* b1  = (const float*)d_in[5];
    const float* Wd  = (const float*)d_in[6];
    const float* bd  = (const float*)d_in[7];
    float* out = (float*)d_out;
    u16* ws = (u16*)d_ws;

    hipLaunchKernelGGL(prepack, dim3(1856), dim3(256), 0, stream, W0, W1, ws);

    void* args[] = { (void*)&x, (void*)&emb, (void*)&W0, (void*)&b0, (void*)&W1,
                     (void*)&b1, (void*)&Wd, (void*)&bd, (void*)&out, (void*)&ws };
    hipLaunchCooperativeKernel((void*)lstm_coop, dim3(256), dim3(256), args, 0, stream);
}

// Round 6
// 4850.443 us; speedup vs baseline: 2.9231x; 1.2396x over previous
//
#include <hip/hip_runtime.h>

// Problem constants
#define Tt 256

// ws layout in unsigned shorts (fp16 bit patterns / ints for flags):
//  flags : 256 blocks x 32 ints (128B apart)            [32 KB]
//  h0 [2 parity][64 g][128 row][8]  fp16 frag-major     [256 KB]   (g = col>>3)
//  h1 same                                              [256 KB]
//  w0lo [128 hg][104 kg][16 n][8]  fp16, lo=(w-fp16(w))*1024, block-private frag-lane order
//  w1lo [128 hg][128 kg][16 n][8]
// total = 4,079,616 shorts = 8,159,232 B  (== R5's proven-safe budget)
#define FLAGS_SHORTS 16384
#define H0OFF  16384
#define H1OFF  (H0OFF + 2*64*128*8)
#define W0LOFF (H1OFF + 2*64*128*8)
#define W1LOFF (W0LOFF + 128*104*16*8)
#define HPAR   (64*128*8)            // u16 per parity plane = 65536

typedef _Float16 h8 __attribute__((ext_vector_type(8)));
typedef float    f4 __attribute__((ext_vector_type(4)));
typedef unsigned long long ull;
typedef unsigned short u16;

#define MFMA __builtin_amdgcn_mfma_f32_16x16x32_f16
#define LOSC (1.0f/1024.0f)

__device__ inline u16 h_bits(float f){ union{_Float16 h; u16 s;} u; u.h=(_Float16)f; return u.s; }
__device__ inline float bits_f(u16 s){ union{u16 s2; _Float16 h;} u; u.s2=s; return (float)u.h; }
__device__ inline float sigm(float x){ return 1.f/(1.f+expf(-x)); }

// Coherent 16B A-fragment load: two relaxed agent-scope 8B atomic loads.
// Agent scope => per-XCD-L2 bypass, served by IF$ (proven R2..R5).
// With frag-major h layout these are COALESCED: 16 fm-lanes read contiguous 16B.
__device__ inline h8 ldH(const u16* p){
    union{ ull u[2]; h8 v; } t;
    t.u[0]=__hip_atomic_load((const ull*)p,    __ATOMIC_RELAXED, __HIP_MEMORY_SCOPE_AGENT);
    t.u[1]=__hip_atomic_load((const ull*)(p+4),__ATOMIC_RELAXED, __HIP_MEMORY_SCOPE_AGENT);
    return t.v;
}

// ---------------- pre-pack W lo-planes (fp16, x1024) block-private frag-lane order ----------------
// one thread per (hg,kg,n) entry writing 8 u16; grid 1856*256 = 475,136 = 128*(104+128)*16
__global__ __launch_bounds__(256) void prepack(const float* __restrict__ W0,
                                               const float* __restrict__ W1,
                                               u16* __restrict__ ws) {
    int idx = blockIdx.x * 256 + threadIdx.x;
    const int NW0 = 128 * 104 * 16;
    if (idx < NW0) {
        int hg  = idx / (104 * 16);
        int rem = idx - hg * (104 * 16);
        int kg = rem >> 4, n = rem & 15;
        int col = ((n >> 2) << 9) + (hg << 2) + (n & 3);
        u16 t[8];
#pragma unroll
        for (int j = 0; j < 8; j++) {
            int k = kg * 8 + j;
            float w = 0.f;
            if (k < 300) w = W0[k * 2048 + col];
            else if (k >= 320) w = W0[(k - 20) * 2048 + col];
            _Float16 wh = (_Float16)w;
            t[j] = h_bits((w - (float)wh) * 1024.0f);
        }
#pragma unroll
        for (int j = 0; j < 8; j++) ws[W0LOFF + (size_t)idx * 8 + j] = t[j];
    } else {
        int i2 = idx - NW0;
        if (i2 < 128 * 128 * 16) {
            int hg  = i2 >> 11;            // / (128*16)
            int rem = i2 & 2047;
            int kg = rem >> 4, n = rem & 15;
            int col = ((n >> 2) << 9) + (hg << 2) + (n & 3);
            u16 t[8];
#pragma unroll
            for (int j = 0; j < 8; j++) {
                float w = W1[(kg * 8 + j) * 2048 + col];
                _Float16 wh = (_Float16)w;
                t[j] = h_bits((w - (float)wh) * 1024.0f);
            }
#pragma unroll
            for (int j = 0; j < 8; j++) ws[W1LOFF + (size_t)i2 * 8 + j] = t[j];
        }
    }
}

// Fence-free split barrier (proven R2..R5).
__device__ inline void barrier_arrive(int* __restrict__ flags, int tid, int bid, int target) {
    __builtin_amdgcn_s_waitcnt(0);
    __syncthreads();
    if (tid == 0)
        __hip_atomic_store(flags + bid * 32, target, __ATOMIC_RELAXED, __HIP_MEMORY_SCOPE_AGENT);
}
__device__ inline void barrier_wait(int* __restrict__ flags, int tid, int target) {
    while (__hip_atomic_load(flags + tid * 32, __ATOMIC_RELAXED, __HIP_MEMORY_SCOPE_AGENT) < target)
        __builtin_amdgcn_s_sleep(1);
    __syncthreads();
}

struct X2 { f4 h, l; };

// ---------------- persistent cooperative LSTM kernel ----------------
// grid 256 x 256. block = (bq = blockIdx>>7: 64-row batch half, hg = blockIdx&127: 4 h-cols
// -> 16 gate cols). Structure identical to R5; only h / W-lo global layouts changed to
// fragment-major so every coherent gather is coalesced (16 lanes x contiguous 16B).
__global__ __launch_bounds__(256, 1) void lstm_coop(
    const int* __restrict__ x, const float* __restrict__ emb,
    const float* __restrict__ W0, const float* __restrict__ b0,
    const float* __restrict__ W1, const float* __restrict__ b1,
    const float* __restrict__ Wd, const float* __restrict__ bd,
    float* __restrict__ out, u16* __restrict__ ws) {

    const int tid  = threadIdx.x;
    const int lane = tid & 63;
    const int wave = tid >> 6;        // 0..3 : m-tile (16 rows each)
    const int quad = lane >> 4;       // 0..3 : k-chunk of 8 in frags
    const int fm   = lane & 15;       // A: m, B: n, C/D: col
    const int bq = blockIdx.x >> 7;
    const int hg = blockIdx.x & 127;

    __shared__ u16   w0hi[104 * 16 * 8];  // 26,624 B (fp16 bits)
    __shared__ u16   w1hi[128 * 16 * 8];  // 32,768 B
    __shared__ float csm[64 * 17];        //  4,352 B  (63,744 B total)

    int* flags = (int*)ws;
    const u16* w0lo = ws + W0LOFF + (size_t)hg * 104 * 16 * 8;   // block-private slice
    const u16* w1lo = ws + W1LOFF + (size_t)hg * 128 * 16 * 8;

    // --- fill LDS hi-planes (fp16) of this block's 16 weight columns, frag layout [kg][n][8] ---
    for (int i = tid; i < 104 * 16 * 8; i += 256) {
        int kg = i >> 7; int rem = i & 127; int n = rem >> 3; int j = rem & 7;
        int k = kg * 8 + j;
        int col = ((n >> 2) << 9) + (hg << 2) + (n & 3);
        float w = 0.f;
        if (k < 300) w = W0[k * 2048 + col];
        else if (k >= 320) w = W0[(k - 20) * 2048 + col];
        w0hi[i] = h_bits(w);
    }
    for (int i = tid; i < 128 * 16 * 8; i += 256) {
        int kg = i >> 7; int rem = i & 127; int n = rem >> 3; int j = rem & 7;
        int k = kg * 8 + j;
        int col = ((n >> 2) << 9) + (hg << 2) + (n & 3);
        w1hi[i] = h_bits(W1[k * 2048 + col]);
    }

    // h addressing helpers (frag-major): u16 index within a parity plane for (row, block h-col c)
    //   g = hg>>1 (all 4 block cols share one 8-group), j = (hg&1)*4 + c
    const int hbase = ((hg >> 1) * 128) * 8 + (hg & 1) * 4;    // + row*8 + c

    // --- zero-init this block's h cells: h0 parity 0 and h1 parity 1 ---
    if (tid < 128) {
        int row = bq * 64 + (tid >> 1);
        int c = (tid & 1) << 1;                                // even col pair
        unsigned int* p0 = (unsigned int*)(ws + H0OFF + 0 * HPAR + hbase + row * 8 + c);
        unsigned int* p1 = (unsigned int*)(ws + H1OFF + 1 * HPAR + hbase + row * 8 + c);
        __hip_atomic_store(p0, 0u, __ATOMIC_RELAXED, __HIP_MEMORY_SCOPE_AGENT);
        __hip_atomic_store(p1, 0u, __ATOMIC_RELAXED, __HIP_MEMORY_SCOPE_AGENT);
    }

    const int arow   = bq * 64 + wave * 16 + fm;  // A-frag row (batch index)
    const int actm   = tid >> 2;
    const int acthc  = tid & 3;
    const int actrow = bq * 64 + actm;
    const int actcol = (hg << 2) + acthc;

    const float b0i = b0[actcol], b0j = b0[512+actcol], b0f = b0[1024+actcol], b0o = b0[1536+actcol];
    const float b1i = b1[actcol], b1j = b1[512+actcol], b1f = b1[1024+actcol], b1o = b1[1536+actcol];

    float c0s = 0.f, c1s = 0.f;

    // x-part GEMM of layer 0 for timestep pp (kt 0..9), recurrence-independent;
    // runs inside the barrier arrive->wait window.
    auto xgemm = [&](int pp) -> X2 {
        X2 a; a.h = (f4){0,0,0,0}; a.l = a.h;
        int xi = x[arow * Tt + pp];
        xi = (xi < 0) ? 0 : ((xi >= 50000) ? 49999 : xi);
        const float* embrow = emb + (size_t)xi * 300;
#pragma unroll
        for (int kt = 0; kt < 10; kt++) {
            int kbase = kt * 32 + quad * 8;
            h8 af;
            if (kt < 9) {
                f4 u0 = *(const f4*)(embrow + kbase);
                f4 u1 = *(const f4*)(embrow + kbase + 4);
#pragma unroll
                for (int e = 0; e < 4; e++) { af[e] = (_Float16)u0[e]; af[4+e] = (_Float16)u1[e]; }
            } else {
#pragma unroll
                for (int e = 0; e < 8; e++) { int kk = kbase + e; af[e] = (_Float16)((kk < 300) ? embrow[kk] : 0.f); }
            }
            int kg = kt * 4 + quad;
            a.h = MFMA(af, *(const h8*)&w0hi[(kg * 16 + fm) * 8], a.h, 0,0,0);
            a.l = MFMA(af, *(const h8*)(w0lo + (kg * 16 + fm) * 8), a.l, 0,0,0);
        }
        return a;
    };

    barrier_arrive(flags, tid, blockIdx.x, 1);
    X2 accx = xgemm(0);
    barrier_wait(flags, tid, 1);

    for (int p = 0; p <= Tt; ++p) {
        const int par = p & 1, wpar = 1 - (p & 1);
        // per-lane A-row base pointers into frag-major planes
        const u16* h0p = ws + H0OFF + par * HPAR + arow * 8;

        if (p >= 1) {   // ---- layer 1 for t=p-1 : g1 = [h0(p-1) | h1(p-2)] @ W1 ----
            f4 aH = (f4){0,0,0,0}, aL = aH;
            const u16* h1p = ws + H1OFF + par * HPAR + arow * 8;
#pragma unroll 8
            for (int kt = 0; kt < 32; kt++) {
                h8 af = (kt < 16) ? ldH(h0p + (kt * 4 + quad) * 1024)
                                  : ldH(h1p + ((kt - 16) * 4 + quad) * 1024);
                int kg = kt * 4 + quad;
                aH = MFMA(af, *(const h8*)&w1hi[(kg * 16 + fm) * 8], aH, 0,0,0);
                aL = MFMA(af, *(const h8*)(w1lo + (kg * 16 + fm) * 8), aL, 0,0,0);
            }
#pragma unroll
            for (int r = 0; r < 4; r++)
                csm[(wave * 16 + quad * 4 + r) * 17 + fm] = aH[r] + aL[r] * LOSC;
            __syncthreads();
            {   // activation: gates i,j,f,o at in-block cols hc, 4+hc, 8+hc, 12+hc
                float gi = csm[actm * 17 + acthc]      + b1i;
                float gj = csm[actm * 17 + 4 + acthc]  + b1j;
                float gf = csm[actm * 17 + 8 + acthc]  + b1f;
                float go = csm[actm * 17 + 12 + acthc] + b1o;
                c1s = c1s * sigm(gf + 1.f) + sigm(gi) * tanhf(gj);
                float h = tanhf(c1s) * sigm(go);
                u16 hb = h_bits(h);
                unsigned int pk = (unsigned int)hb | (((unsigned int)(u16)__shfl_xor((int)hb, 1, 64)) << 16);
                if (!(acthc & 1)) {
                    unsigned int* d = (unsigned int*)(ws + H1OFF + wpar * HPAR + hbase + actrow * 8 + acthc);
                    __hip_atomic_store(d, pk, __ATOMIC_RELAXED, __HIP_MEMORY_SCOPE_AGENT);
                }
            }
            __syncthreads();
        }

        if (p < Tt) {   // ---- layer 0 h-part for t=p (x-part already in accx) ----
            f4 aH = accx.h, aL = accx.l;
#pragma unroll 8
            for (int kt = 10; kt < 26; kt++) {
                h8 af = ldH(h0p + (kt * 4 + quad - 40) * 1024);
                int kg = kt * 4 + quad;
                aH = MFMA(af, *(const h8*)&w0hi[(kg * 16 + fm) * 8], aH, 0,0,0);
                aL = MFMA(af, *(const h8*)(w0lo + (kg * 16 + fm) * 8), aL, 0,0,0);
            }
#pragma unroll
            for (int r = 0; r < 4; r++)
                csm[(wave * 16 + quad * 4 + r) * 17 + fm] = aH[r] + aL[r] * LOSC;
            __syncthreads();
            {
                float gi = csm[actm * 17 + acthc]      + b0i;
                float gj = csm[actm * 17 + 4 + acthc]  + b0j;
                float gf = csm[actm * 17 + 8 + acthc]  + b0f;
                float go = csm[actm * 17 + 12 + acthc] + b0o;
                c0s = c0s * sigm(gf + 1.f) + sigm(gi) * tanhf(gj);
                float h = tanhf(c0s) * sigm(go);
                u16 hb = h_bits(h);
                unsigned int pk = (unsigned int)hb | (((unsigned int)(u16)__shfl_xor((int)hb, 1, 64)) << 16);
                if (!(acthc & 1)) {
                    unsigned int* d = (unsigned int*)(ws + H0OFF + wpar * HPAR + hbase + actrow * 8 + acthc);
                    __hip_atomic_store(d, pk, __ATOMIC_RELAXED, __HIP_MEMORY_SCOPE_AGENT);
                }
            }
        }

        barrier_arrive(flags, tid, blockIdx.x, p + 2);
        if (p + 1 < Tt) accx = xgemm(p + 1);
        barrier_wait(flags, tid, p + 2);
    }

    // ---- final logits: h1(T-1) lives in parity 1 (frag-major addressing) ----
    if (blockIdx.x == 0) {
        int b = tid >> 1, jj = tid & 1;
        float sum = bd[jj];
        const u16* hh = ws + H1OFF + 1 * HPAR;
        for (int g = 0; g < 64; g++) {
#pragma unroll
            for (int j4 = 0; j4 < 8; j4 += 4) {
                ull u = __hip_atomic_load((const ull*)(hh + (g * 128 + b) * 8 + j4),
                                          __ATOMIC_RELAXED, __HIP_MEMORY_SCOPE_AGENT);
#pragma unroll
                for (int e = 0; e < 4; e++)
                    sum += bits_f((u16)(u >> (16 * e))) * Wd[(g * 8 + j4 + e) * 2 + jj];
            }
        }
        out[b * 2 + jj] = sum;
    }
}

extern "C" void kernel_launch(void* const* d_in, const int* in_sizes, int n_in,
                              void* d_out, int out_size, void* d_ws, size_t ws_size,
                              hipStream_t stream) {
    const int*   x   = (const int*)d_in[0];
    const float* emb = (const float*)d_in[1];
    const float* W0  = (const float*)d_in[2];
    const float* b0  = (const float*)d_in[3];
    const float* W1  = (const float*)d_in[4];
    const float* b1  = (const float*)d_in[5];
    const float* Wd  = (const float*)d_in[6];
    const float* bd  = (const float*)d_in[7];
    float* out = (float*)d_out;
    u16* ws = (u16*)d_ws;

    hipLaunchKernelGGL(prepack, dim3(1856), dim3(256), 0, stream, W0, W1, ws);

    void* args[] = { (void*)&x, (void*)&emb, (void*)&W0, (void*)&b0, (void*)&W1,
                     (void*)&b1, (void*)&Wd, (void*)&bd, (void*)&out, (void*)&ws };
    hipLaunchCooperativeKernel((void*)lstm_coop, dim3(256), dim3(256), args, 0, stream);
}